// Round 5
// baseline (523.434 us; speedup 1.0000x reference)
//
#include <hip/hip_runtime.h>

// Locally-connected conv, MI355X. Round 6: R5 + T3/T4 no-drain pipeline.
// R2-R5 post-mortem: all designs capped at ~2-2.9 TB/s. Unified model:
// HBM RTT under load ~2700-3000 cy; every design drained outstanding
// loads (compiler vmcnt(0) before __syncthreads, or shallow vmcnt(2)
// ping-pong) -> Little's law caps BW at ~2 TB/s. Fix: counted vmcnt
// across raw barriers, ring-3 half-tiles, ~54 KB/CU continuously in
// flight -> predicted 4.5-6 TB/s on the 302 MB weight stream.
//  - Block = (h, 4-pos w strip) x 64 o; 8 phases, one contiguous
//    36,864B weight half-tile (pos, o-half) per phase; each of the 4
//    waves streams its quarter (9 x 1KB glds, src pre-swizzled q^=row&7).
//  - Loop: s_waitcnt vmcnt(9) [ph+1 stays in flight] -> raw s_barrier ->
//    stage ph+2 into slot (ph+2)%3 [= (ph-1)%3, provably consumed] ->
//    (oh==ph&1) waves compute 9 MFMA steps into accP[pos] (static index
//    via full unroll; no per-phase Pred reduce, no second barrier).
//  - End: kh0 writes accP to outF (32KB, fits in dead ring slot 0),
//    barrier, kh1 adds, barrier, float4 stores + bias (R5 epilogue).
//  - LDS 147,456 = ring 3x36,864 + Xl 36,864. 1 block/CU, grid 1024,
//    XCD clustering unchanged (16 ws of one h adjacent on one XCD).

typedef __attribute__((ext_vector_type(8))) short short8;
typedef __attribute__((ext_vector_type(16))) float f32x16;
typedef __attribute__((ext_vector_type(4))) float f32x4;

__device__ __forceinline__ unsigned f2bf(float f) {
    unsigned u = __builtin_bit_cast(unsigned, f);
    return (u + 0x7FFFu + ((u >> 16) & 1u)) >> 16;   // RNE, finite inputs
}

__device__ __forceinline__ void glds16(const float* g, float* l) {
    __builtin_amdgcn_global_load_lds(
        (const __attribute__((address_space(1))) void*)g,
        (__attribute__((address_space(3))) void*)l, 16, 0, 0);
}

__global__ __launch_bounds__(256, 1) void lcconv_kernel(
    const float* __restrict__ xg,    // [32][32][64][64]
    const float* __restrict__ wg,    // [64][64][64][32][3][3]
    const float* __restrict__ bg,    // [64][64][64]
    float* __restrict__ outg)        // [32][64][64][64]
{
    __shared__ __align__(16) unsigned char Lds[147456];
    unsigned short* Xl = (unsigned short*)(Lds + 110592);  // 36,864 B

    const int tid = threadIdx.x;
    const int Bq  = blockIdx.x;
    // all 16 ws of one h land on one XCD in adjacent slots
    const int xcd = Bq & 7;
    const int idx = Bq >> 3;                 // 0..127
    const int h   = xcd * 8 + (idx >> 4);
    const int w0  = (idx & 15) * 4;

    const int lane = tid & 63;
    const int wv   = tid >> 6;
    const int n    = lane & 31;
    const int g    = lane >> 5;
    const int oh   = wv >> 1;                // o-half this wave computes
    const int kh   = wv & 1;                 // K-half (144 each)

    // per-lane glds src byte offsets within a 36,864B half-tile:
    // phys 16B slot P holds global slot r*72 + (q ^ (r&7)) (involution).
    int srcoff[9];
#pragma unroll
    for (int j = 0; j < 9; j++) {
        int P  = wv * 576 + j * 64 + lane;
        int rp = (P * 3641) >> 18;           // floor(P/72), exact here
        int qp = P - rp * 72;
        srcoff[j] = rp * 1152 + ((qp ^ (rp & 7)) << 4);
    }

    const char* wtile = (const char*)(wg + (h * 64 + w0) * 64 * 288);
    // half-tile ph: byte off (ph>>1)*73728 + (ph&1)*36864; ring slot ph%3

    // ---- prologue: issue phases 0,1 (x-build + its syncthreads cover them)
#pragma unroll
    for (int ph = 0; ph < 2; ph++) {
        const char* rb = wtile + (ph >> 1) * 73728 + (ph & 1) * 36864;
        float* db = (float*)(Lds + (ph % 3) * 36864 + wv * 9216);
#pragma unroll
        for (int j = 0; j < 9; j++)
            glds16((const float*)(rb + srcoff[j]), db + j * 256);
    }

    // ---- build raw x tile once: Xl[b][(c+b)&31][y3][xt], xt -> w = w0-1+xt
#pragma unroll
    for (int t = 0; t < 12; t++) {
        int task = t * 256 + tid;            // 3072 rows of 6 elems
        int b   = task / 96;
        int rem = task - b * 96;
        int c   = rem / 3;
        int y3  = rem - c * 3;
        int y   = h + y3 - 1;
        float v0 = 0.f, v1 = 0.f, v2 = 0.f, v3 = 0.f, v4 = 0.f, v5 = 0.f;
        if ((unsigned)y < 64u) {
            const float* row = xg + ((b * 32 + c) * 64 + y) * 64;
            float4 m = *(const float4*)(row + w0);   // w0 % 4 == 0: aligned
            v1 = m.x; v2 = m.y; v3 = m.z; v4 = m.w;
            if (w0 > 0)      v0 = row[w0 - 1];
            if (w0 + 4 < 64) v5 = row[w0 + 4];
        }
        int cr = (c + b) & 31;
        unsigned* dst = (unsigned*)(Xl + ((b * 32 + cr) * 3 + y3) * 6);
        dst[0] = f2bf(v0) | (f2bf(v1) << 16);
        dst[1] = f2bf(v2) | (f2bf(v3) << 16);
        dst[2] = f2bf(v4) | (f2bf(v5) << 16);
    }
    __syncthreads();   // Xl ready; drains prologue glds (prologue-only cost)

    f32x16 accP[4];
#pragma unroll
    for (int p = 0; p < 4; p++)
#pragma unroll
        for (int i = 0; i < 16; i++) accP[p][i] = 0.f;

    const int kh144  = kh * 144, kh36 = kh * 36;
    const int g8     = g * 8,    g2   = g * 2;
    const int nn1152 = n * 1152, n7   = n & 7;
    const int ab0    = n * 576;

#pragma unroll
    for (int ph = 0; ph < 8; ph++) {
        // T4: ph+1's 9 glds stay in flight; only ensure ph's landed.
        if (ph < 7) asm volatile("s_waitcnt vmcnt(9)" ::: "memory");
        else        asm volatile("s_waitcnt vmcnt(0)" ::: "memory");
        __builtin_amdgcn_sched_barrier(0);
        __builtin_amdgcn_s_barrier();      // raw: no compiler vmcnt(0) drain
        __builtin_amdgcn_sched_barrier(0);

        if (ph + 2 < 8) {   // stage ph+2 into slot (ph-1)%3 (consumed)
            const char* rb = wtile + ((ph + 2) >> 1) * 73728
                                   + ((ph + 2) & 1) * 36864;
            float* db = (float*)(Lds + ((ph + 2) % 3) * 36864 + wv * 9216);
#pragma unroll
            for (int j = 0; j < 9; j++)
                glds16((const float*)(rb + srcoff[j]), db + j * 256);
        }

        if (oh == (ph & 1)) {
            const char* Wt  = (const char*)Lds + (ph % 3) * 36864;
            const int   pos = ph >> 1;
            const int   ab  = ab0 + pos;
#pragma unroll
            for (int s = 0; s < 9; s++) {
                int q0 = kh36 + s * 4 + g2;          // even -> pair {q0,q0+1}
                f32x4 wa = *(const f32x4*)(Wt + nn1152 + (((q0    ) ^ n7) << 4));
                f32x4 wb = *(const f32x4*)(Wt + nn1152 + (((q0 + 1) ^ n7) << 4));

                short8 a;
#pragma unroll
                for (int e = 0; e < 8; e++) {
                    int k  = kh144 + s * 16 + g8 + e;
                    int c  = (k * 456) >> 12;        // floor(k/9), k < 288
                    int t2 = k - c * 9;
                    int i  = (t2 * 11) >> 5;         // floor(t2/3), t2 < 9
                    int j2 = t2 - i * 3;
                    int cr = (c + n) & 31;
                    a[e] = (short)Xl[ab + cr * 18 + i * 6 + j2];
                }

                short8 w8;
                w8[0] = (short)f2bf(wa[0]); w8[1] = (short)f2bf(wa[1]);
                w8[2] = (short)f2bf(wa[2]); w8[3] = (short)f2bf(wa[3]);
                w8[4] = (short)f2bf(wb[0]); w8[5] = (short)f2bf(wb[1]);
                w8[6] = (short)f2bf(wb[2]); w8[7] = (short)f2bf(wb[3]);

                accP[pos] = __builtin_amdgcn_mfma_f32_32x32x16_bf16(
                    a, w8, accP[pos], 0, 0, 0);
            }
        }
    }

    // ---- epilogue: kh0 writes, kh1 adds, then float4 stores + bias.
    // outF (32KB) fits entirely in ring slot 0 (dead: last used ph6, and
    // all ph<=6 compute finished before the ph7 barrier all waves crossed).
    float* outF = (float*)Lds;   // [oh][pos][b][n] = oh*4096+pos*1024+b*32+n
    if (kh == 0) {
#pragma unroll
        for (int pos = 0; pos < 4; pos++)
#pragma unroll
            for (int r = 0; r < 16; r++) {
                int b = (r & 3) + 8 * (r >> 2) + 4 * g;   // verified C layout
                outF[((oh * 4 + pos) * 32 + b) * 32 + n] = accP[pos][r];
            }
    }
    __syncthreads();
    if (kh == 1) {
#pragma unroll
        for (int pos = 0; pos < 4; pos++)
#pragma unroll
            for (int r = 0; r < 16; r++) {
                int b = (r & 3) + 8 * (r >> 2) + 4 * g;
                outF[((oh * 4 + pos) * 32 + b) * 32 + n] += accP[pos][r];
            }
    }
    __syncthreads();

#pragma unroll
    for (int it = 0; it < 8; it++) {
        int id = it * 256 + tid;
        int b  = id >> 6;
        int o  = id & 63;
        const float* src = outF + (o >> 5) * 4096 + b * 32 + (o & 31);
        float4 v;
        v.x = src[0];
        v.y = src[1024];
        v.z = src[2048];
        v.w = src[3072];
        const float4 bb = *(const float4*)(bg + (o * 64 + h) * 64 + w0);
        v.x += bb.x; v.y += bb.y; v.z += bb.z; v.w += bb.w;
        *(float4*)(outg + ((b * 64 + o) * 64 + h) * 64 + w0) = v;
    }
}

extern "C" void kernel_launch(void* const* d_in, const int* in_sizes, int n_in,
                              void* d_out, int out_size, void* d_ws, size_t ws_size,
                              hipStream_t stream) {
    const float* x = (const float*)d_in[0];
    const float* w = (const float*)d_in[1];
    const float* b = (const float*)d_in[2];
    float* out = (float*)d_out;
    lcconv_kernel<<<dim3(1024), dim3(256), 0, stream>>>(x, w, b, out);
}

// Round 6
// 469.609 us; speedup vs baseline: 1.1146x; 1.1146x over previous
//
#include <hip/hip_runtime.h>

// Locally-connected conv, MI355X. Round 7: minimal inner loop + occupancy.
// R6 post-mortem: not memory-limited — loop-limited. 1 blk/CU (4 waves,
// 1/SIMD), 2/4 waves idle per phase, ~100+ instrs per MFMA step (gathers,
// f2bf, ring addressing) fully latency-exposed. R7:
//  - Block = (h, 2-w strip) x 64 o; 4 waves = (pos, oh); each wave owns one
//    32x32 output + its own 36,864B weight stream -> ZERO K-loop barriers.
//  - A-side: im2col P[2 pos][32 b][312 u16] built once in LDS (stride 312
//    -> 4-way banks). A-frag = ONE ds_read_b128 at compile-time offset.
//  - W-side: per-wave ring-5 x 2KB glds chunks (1 chunk = 1 K-step = 32
//    o-rows x 64B, src pre-swizzled q^=r&3). Macro-unrolled 18 steps with
//    literal s_waitcnt vmcnt(N): issue chunk ks+4, wait vmcnt(8) -> 8-10KB
//    in flight/wave, lead-4 (~6.5Kcy slack). Step = 3 ds_read + 20 VALU
//    + 1 MFMA (~26 instrs, was ~100+).
//  - LDS 80,896 = P 39,936 + ring 40,960 -> 2 blocks/CU = 8 waves (2/SIMD).
//  - Grid 2048; XCD map: 32 w-strips of one h adjacent on one XCD (R6's
//    verified WRITE=1.0x mapping). Epilogue: LDS transpose -> float2+bias.

typedef __attribute__((ext_vector_type(8))) short short8;
typedef __attribute__((ext_vector_type(16))) float f32x16;
typedef __attribute__((ext_vector_type(4))) float f32x4;

__device__ __forceinline__ unsigned f2bf(float f) {
    unsigned u = __builtin_bit_cast(unsigned, f);
    return (u + 0x7FFFu + ((u >> 16) & 1u)) >> 16;   // RNE, finite inputs
}

__device__ __forceinline__ void glds16(const float* g, float* l) {
    __builtin_amdgcn_global_load_lds(
        (const __attribute__((address_space(1))) void*)g,
        (__attribute__((address_space(3))) void*)l, 16, 0, 0);
}

#define P_STRIDE 312                   // u16; 288 used + 24 pad (4-way banks)
#define P_POS    (32 * P_STRIDE)
#define RING_OFF 39936                 // bytes; ring = 4 waves x 5 x 2048B

#define STEP(KS, VM)  do {                                                    \
    if ((KS) + 4 < 18) {                                                      \
        glds16(sA + ((KS) + 4) * 16, ringw + (((KS) + 4) % 5) * 512);         \
        glds16(sB + ((KS) + 4) * 16, ringw + (((KS) + 4) % 5) * 512 + 256);   \
    }                                                                         \
    asm volatile("s_waitcnt vmcnt(" #VM ")" ::: "memory");                    \
    __builtin_amdgcn_sched_barrier(0);                                        \
    {                                                                         \
        const char* wt = (const char*)(ringw + ((KS) % 5) * 512);             \
        f32x4 wa = *(const f32x4*)(wt + rdA);                                 \
        f32x4 wb = *(const f32x4*)(wt + rdB);                                 \
        short8 pa = *(const short8*)(Pl16 + pbase + (KS) * 16);               \
        short8 w8;                                                            \
        w8[0] = (short)f2bf(wa[0]); w8[1] = (short)f2bf(wa[1]);               \
        w8[2] = (short)f2bf(wa[2]); w8[3] = (short)f2bf(wa[3]);               \
        w8[4] = (short)f2bf(wb[0]); w8[5] = (short)f2bf(wb[1]);               \
        w8[6] = (short)f2bf(wb[2]); w8[7] = (short)f2bf(wb[3]);               \
        acc = __builtin_amdgcn_mfma_f32_32x32x16_bf16(pa, w8, acc, 0, 0, 0);  \
    }                                                                         \
} while (0)

__global__ __launch_bounds__(256, 2) void lcconv_kernel(
    const float* __restrict__ xg,    // [32][32][64][64]
    const float* __restrict__ wg,    // [64][64][64][32][3][3]
    const float* __restrict__ bg,    // [64][64][64]
    float* __restrict__ outg)        // [32][64][64][64]
{
    __shared__ __align__(16) unsigned char Lds[80896];
    unsigned short* Pl16 = (unsigned short*)Lds;

    const int tid = threadIdx.x;
    const int B   = blockIdx.x;
    // 32 w-strips of one h adjacent on one XCD (write-merge + x L2 locality)
    const int xcd = B & 7;
    const int idx = B >> 3;                  // 0..255
    const int h   = xcd * 8 + (idx >> 5);
    const int w0  = (idx & 31) * 2;          // 2-wide w strip (even)

    const int lane = tid & 63;
    const int wv   = tid >> 6;
    const int n    = lane & 31;              // A row (b) == B col (o)
    const int g    = lane >> 5;
    const int pos  = wv >> 1;                // w = w0 + pos
    const int oh   = wv & 1;                 // o-half

    float* ringw = (float*)(Lds + RING_OFF) + wv * 2560;   // 10,240 B/wave

    // ---- per-lane glds sources: chunk ks = floats ks*16..+15 of 32 rows.
    // 2 instrs/chunk (16 rows each); phys slot q holds global slot q^(r&3).
    const float* wbase = wg + ((h * 64 + (w0 + pos)) * 64 + oh * 32) * 288;
    const int rA = lane >> 2;                // rows 0..15
    const int rB = 16 + rA;                  // rows 16..31 (same &3)
    const int qs = (lane & 3) ^ (rA & 3);
    const float* sA = wbase + rA * 288 + qs * 4;
    const float* sB = wbase + rB * 288 + qs * 4;

    // reader: lane (n,g) wants global slots {2g,2g+1} of row n
    const int rdA = n * 64 + (((2 * g)     ^ (n & 3)) << 4);
    const int rdB = n * 64 + (((2 * g + 1) ^ (n & 3)) << 4);
    const int pbase = pos * P_POS + n * P_STRIDE + g * 8;   // u16 units

    // ---- prologue: issue chunks 0..3 (x-build + syncthreads cover them)
#pragma unroll
    for (int c0 = 0; c0 < 4; c0++) {
        glds16(sA + c0 * 16, ringw + c0 * 512);
        glds16(sB + c0 * 16, ringw + c0 * 512 + 256);
    }

    // ---- build P (im2col) once: rows (b,c,y3), cols w0-1..w0+2
    const int case2 = (w0 & 3) != 0;   // w0 % 4 == 2
#pragma unroll
    for (int t = 0; t < 12; t++) {
        int task = t * 256 + tid;              // (b*32+c)*3 + y3
        int t3   = (task * 43691) >> 17;       // task/3, exact
        int b = t3 >> 5, c = t3 & 31, y3 = task - t3 * 3;
        int y = h + y3 - 1;
        float c0 = 0.f, c1 = 0.f, c2 = 0.f, c3 = 0.f;   // cols w0-1..w0+2
        if ((unsigned)y < 64u) {
            const float* row = xg + ((b * 32 + c) * 64 + y) * 64;
            float4 m = *(const float4*)(row + (w0 & ~3));
            if (!case2) {
                c1 = m.x; c2 = m.y; c3 = m.z;
                if (w0 > 0) c0 = row[w0 - 1];
            } else {
                c0 = m.y; c1 = m.z; c2 = m.w;
                if (w0 + 2 < 64) c3 = row[w0 + 2];
            }
        }
        int kb = c * 9 + y3 * 3;
        unsigned short* p0 = Pl16 + b * P_STRIDE + kb;
        unsigned short* p1 = p0 + P_POS;
        unsigned short b0 = (unsigned short)f2bf(c0);
        unsigned short b1 = (unsigned short)f2bf(c1);
        unsigned short b2 = (unsigned short)f2bf(c2);
        unsigned short b3 = (unsigned short)f2bf(c3);
        p0[0] = b0; p0[1] = b1; p0[2] = b2;   // pos0: j=0,1,2
        p1[0] = b1; p1[1] = b2; p1[2] = b3;   // pos1: j=0,1,2
    }
    __syncthreads();   // P ready; drains prologue glds (one-time cost)

    f32x16 acc;
#pragma unroll
    for (int i = 0; i < 16; i++) acc[i] = 0.f;

    // ---- K-loop: 18 steps, no barriers, per-wave counted vmcnt
    STEP(0, 8);  STEP(1, 8);  STEP(2, 8);  STEP(3, 8);
    STEP(4, 8);  STEP(5, 8);  STEP(6, 8);  STEP(7, 8);
    STEP(8, 8);  STEP(9, 8);  STEP(10, 8); STEP(11, 8);
    STEP(12, 8); STEP(13, 8); STEP(14, 6); STEP(15, 4);
    STEP(16, 2); STEP(17, 0);

    // ---- epilogue: acc -> LDS transpose (reuse ring) -> float2 + bias
    __syncthreads();
    float* outF = (float*)(Lds + RING_OFF);   // [2 pos][32 b][64 o] = 16 KB
#pragma unroll
    for (int r = 0; r < 16; r++) {
        int b = (r & 3) + 8 * (r >> 2) + 4 * g;   // verified C layout
        outF[(pos * 32 + b) * 64 + oh * 32 + n] = acc[r];
    }
    __syncthreads();

#pragma unroll
    for (int it = 0; it < 8; it++) {
        int id = it * 256 + tid;
        int b = id >> 6, o = id & 63;
        float2 v;
        v.x = outF[b * 64 + o];
        v.y = outF[2048 + b * 64 + o];
        const float2 bb = *(const float2*)(bg + (o * 64 + h) * 64 + w0);
        v.x += bb.x; v.y += bb.y;
        *(float2*)(outg + ((b * 64 + o) * 64 + h) * 64 + w0) = v;
    }
}

extern "C" void kernel_launch(void* const* d_in, const int* in_sizes, int n_in,
                              void* d_out, int out_size, void* d_ws, size_t ws_size,
                              hipStream_t stream) {
    const float* x = (const float*)d_in[0];
    const float* w = (const float*)d_in[1];
    const float* b = (const float*)d_in[2];
    float* out = (float*)d_out;
    lcconv_kernel<<<dim3(2048), dim3(256), 0, stream>>>(x, w, b, out);
}